// Round 11
// baseline (193.050 us; speedup 1.0000x reference)
//
#include <hip/hip_runtime.h>

#pragma clang fp contract(off)

#define NBOX 262144
#define NCLS 80
#define ROWS 85
#define CAP 1024
#define NSUB 8          // sub-buckets per class (contention spreading)
#define SUBCAP 128      // CAP / NSUB; mean load ~82, 5 sigma headroom
#define POOL 8192
#define NBLK 256        // megakernel grid; capacity math guarantees co-residency:
                        // ~21KB LDS, 4 waves/block -> 7 blocks/CU possible, need 1
#define S1PB 1024       // boxes per block in stage1 phase

typedef unsigned long long ull;

__device__ __forceinline__ ull packf2(float a, float b) {
    return ((ull)__float_as_uint(b) << 32) | (ull)__float_as_uint(a);
}

// ---------------- init: zero padded per-(class,sub) counters + pool/done counters
__global__ __launch_bounds__(1024) void k_init(int* __restrict__ cnt_pad,
                                               int* __restrict__ pool_count,
                                               int* __restrict__ done_count) {
    const int t = threadIdx.x;
    for (int i = t; i < NCLS * NSUB * 16; i += 1024) cnt_pad[i] = 0;
    if (t == 0) { *pool_count = 0; *done_count = 0; }
}

// ---------------- manual grid sync: monotonic counter, agent scope (R6-R9 protocol).
// __syncthreads drains vmcnt (agent stores at coherent point) before t0's add;
// readers use agent-scope loads. BOUNDED spin: if sync cannot complete, the kernel
// finishes with wrong output (diagnosable) instead of hanging the container.
__device__ __forceinline__ void gsync(int* done, int target, int t) {
    __syncthreads();
    if (t == 0) {
        __hip_atomic_fetch_add(done, 1, __ATOMIC_RELAXED, __HIP_MEMORY_SCOPE_AGENT);
        int guard = 0;
        while (__hip_atomic_load(done, __ATOMIC_RELAXED,
                                 __HIP_MEMORY_SCOPE_AGENT) < target &&
               ++guard < (1 << 18))
            __builtin_amdgcn_s_sleep(8);
    }
    __syncthreads();
}

// ---------------- single-wave in-register bitonic sort of 512 (8/lane, i = r*64+lane)
__device__ __forceinline__ void bsort512(ull (&x)[8], int lane) {
    #pragma unroll
    for (int k = 2; k <= 512; k <<= 1) {
        #pragma unroll
        for (int j = k >> 1; j >= 64; j >>= 1) {
            const int jr = j >> 6;
            #pragma unroll
            for (int r2 = 0; r2 < 8; r2++) {
                if ((r2 & jr) == 0) {
                    const bool asc = (((r2 << 6) & k) == 0);
                    ull a = x[r2], b = x[r2 | jr];
                    if ((a > b) == asc) { x[r2] = b; x[r2 | jr] = a; }
                }
            }
        }
        #pragma unroll
        for (int j = ((k >> 1) > 32 ? 32 : (k >> 1)); j >= 1; j >>= 1) {
            #pragma unroll
            for (int r2 = 0; r2 < 8; r2++) {
                int i = (r2 << 6) + lane;
                bool asc = ((i & k) == 0);
                ull o = __shfl_xor(x[r2], j);
                bool lower = ((lane & j) == 0);
                ull mn = x[r2] < o ? x[r2] : o;
                ull mx2 = x[r2] < o ? o : x[r2];
                x[r2] = (asc == lower) ? mn : mx2;
            }
        }
    }
}

// ---------------- megakernel: stage1 -> gsync -> per-class NMS -> gsync -> final
__global__ __launch_bounds__(256) void k_mega(const float* __restrict__ det,
                                              int* __restrict__ cnt_pad,
                                              ull* __restrict__ key2,
                                              float* __restrict__ conf2,
                                              float4* __restrict__ box2,
                                              ull* __restrict__ pool_key,
                                              float* __restrict__ pool_conf,
                                              int* __restrict__ pool_cls,
                                              int* __restrict__ pool_count,
                                              int* __restrict__ done_count,
                                              float* __restrict__ out) {
    __shared__ int s_wl[S1PB];
    __shared__ float s_obj[S1PB];
    __shared__ int s_nv;
    __shared__ int s_cnt[NSUB];
    __shared__ ull s_wkey[4];        // per-wave winner mailbox
    __shared__ float s_wbox[4][6];   // x1 y1 x2 y2 area conf
    __shared__ int s_base;
    __shared__ ull pkey[304];
    __shared__ float pconf[304];
    // final-stage shared
    __shared__ int s_hist[256];
    __shared__ int s_wt[4];
    __shared__ int s_stat[4];
    __shared__ ull s_buf[512];
    __shared__ unsigned s_cb[512];
    __shared__ unsigned s_cl[512];

    const int bid = blockIdx.x, t = threadIdx.x, lane = t & 63, wave = t >> 6;

    // ================= stage1: obj-scan + class argmax + bucket scatter =========
    {
        const int b0 = bid << 10;
        const int sb = bid & (NSUB - 1);
        if (t == 0) s_nv = 0;
        __syncthreads();
        float obj[4];
        #pragma unroll
        for (int i = 0; i < 4; i++)
            obj[i] = det[(size_t)(b0 + (i << 8) + t) * ROWS + 4];
        #pragma unroll
        for (int i = 0; i < 4; i++) {
            if (obj[i] >= 0.8f) {                 // CONF_THRES
                int r = atomicAdd(&s_nv, 1);      // LDS atomic; order irrelevant
                s_wl[r] = (i << 8) + t;
                s_obj[r] = obj[i];
            }
        }
        __syncthreads();
        const int nv = s_nv;

        // 16 lanes per valid box; j = k*16 + c covers classes 0..79 exactly
        const int grp = t >> 4, c = t & 15;
        #pragma unroll 2
        for (int r0 = 0; r0 < nv; r0 += 16) {
            int widx = r0 + grp;
            if (widx < nv) {                      // group-uniform guard
                int b = s_wl[widx];
                const float* p = det + (size_t)(b0 + b) * ROWS;
                float aux = (c < 5) ? p[c] : 0.0f;    // x y w h obj
                float v0 = p[5 + c];
                float v1 = p[21 + c];
                float v2 = p[37 + c];
                float v3 = p[53 + c];
                float v4 = p[69 + c];
                float mv = v0; int mj = c;
                if (v1 > mv) { mv = v1; mj = 16 + c; }   // ascending j, strict >
                if (v2 > mv) { mv = v2; mj = 32 + c; }
                if (v3 > mv) { mv = v3; mj = 48 + c; }
                if (v4 > mv) { mv = v4; mj = 64 + c; }
                #pragma unroll
                for (int off = 8; off; off >>= 1) {      // group argmax, ties smaller j
                    float ov = __shfl_xor(mv, off);
                    int oj = __shfl_xor(mj, off);
                    if (ov > mv || (ov == mv && oj < mj)) { mv = ov; mj = oj; }
                }
                int gb = lane & 48;                      // group base within wave
                float x = __shfl(aux, gb + 0);
                float y = __shfl(aux, gb + 1);
                float w = __shfl(aux, gb + 2);
                float h = __shfl(aux, gb + 3);
                if (c == 0) {
                    float ob = s_obj[widx];
                    float score = ob * mv;
                    float hw = w * 0.5f, hh = h * 0.5f;
                    int gi = b0 + b;
                    int r = atomicAdd(&cnt_pad[((mj * NSUB + sb) << 4)], 1);
                    if (r < SUBCAP) {
                        int pos = (mj << 10) + (sb << 7) + r;
                        // agent-scope stores: visible at coherent point, no fence needed
                        __hip_atomic_store(&key2[pos],
                            ((ull)(~__float_as_uint(score)) << 32) | (unsigned)gi,
                            __ATOMIC_RELAXED, __HIP_MEMORY_SCOPE_AGENT);
                        __hip_atomic_store(&conf2[pos], mv,
                            __ATOMIC_RELAXED, __HIP_MEMORY_SCOPE_AGENT);
                        ull* bp = (ull*)&box2[pos];
                        __hip_atomic_store(bp + 0, packf2(x - hw, y - hh),
                            __ATOMIC_RELAXED, __HIP_MEMORY_SCOPE_AGENT);
                        __hip_atomic_store(bp + 1, packf2(x + hw, y + hh),
                            __ATOMIC_RELAXED, __HIP_MEMORY_SCOPE_AGENT);
                    }
                }
            }
        }
    }

    gsync(done_count, NBLK, t);       // all stage1 writes at coherent point

    // ================= per-class 4-wave NMS (blocks 0..79) ======================
    if (bid < NCLS) {
        const int c = bid;
        const int s0 = c << 10;
        ull k4[4]; float x1[4], y1[4], x2[4], y2[4], ar[4], cf[4];
        #pragma unroll
        for (int j = 0; j < 4; j++) {
            int pos = s0 + (wave << 8) + (j << 6) + lane;   // coalesced segments
            k4[j] = __hip_atomic_load(&key2[pos], __ATOMIC_RELAXED,
                                      __HIP_MEMORY_SCOPE_AGENT);
            ull* bp = (ull*)&box2[pos];
            ull blo = __hip_atomic_load(bp + 0, __ATOMIC_RELAXED,
                                        __HIP_MEMORY_SCOPE_AGENT);
            ull bhi = __hip_atomic_load(bp + 1, __ATOMIC_RELAXED,
                                        __HIP_MEMORY_SCOPE_AGENT);
            x1[j] = __uint_as_float((unsigned)blo);
            y1[j] = __uint_as_float((unsigned)(blo >> 32));
            x2[j] = __uint_as_float((unsigned)bhi);
            y2[j] = __uint_as_float((unsigned)(bhi >> 32));
            cf[j] = __hip_atomic_load(&conf2[pos], __ATOMIC_RELAXED,
                                      __HIP_MEMORY_SCOPE_AGENT);
        }
        if (t < NSUB)
            s_cnt[t] = min(__hip_atomic_load(&cnt_pad[((c * NSUB + t) << 4)],
                                             __ATOMIC_RELAXED, __HIP_MEMORY_SCOPE_AGENT),
                           SUBCAP);
        __syncthreads();
        #pragma unroll
        for (int j = 0; j < 4; j++) {
            int pos = (wave << 8) + (j << 6) + lane;
            bool ok = (pos & (SUBCAP - 1)) < s_cnt[pos >> 7];   // gaps masked
            if (!ok) {
                k4[j] = ~0ULL;
                x1[j] = 0.f; y1[j] = 0.f; x2[j] = 0.f; y2[j] = 0.f; cf[j] = 0.f;
            }
            ar[j] = (x2[j] - x1[j] + 1.0f) * (y2[j] - y1[j] + 1.0f);
        }

        int np = 0;
        while (np < 300) {
            // wave-local argmin over 4 slots
            ull va = k4[0]; int ia = 0;
            if (k4[1] < va) { va = k4[1]; ia = 1; }
            ull vb = k4[2]; int ib = 2;
            if (k4[3] < vb) { vb = k4[3]; ib = 3; }
            ull lm = va; int lj = ia;
            if (vb < va) { lm = vb; lj = ib; }
            unsigned lo = (unsigned)lm;
            unsigned hi = (unsigned)(lm >> 32);
            unsigned mh = hi;
            #pragma unroll
            for (int off = 32; off; off >>= 1) {
                unsigned o = __shfl_xor(mh, off);
                mh = o < mh ? o : mh;
            }
            ull wb = __ballot(hi == mh);
            ull wm; int wl;
            if (__popcll(wb) != 1) {              // tie / possible-empty fallback
                ull g = (hi == mh) ? lm : ~0ULL;
                #pragma unroll
                for (int off = 32; off; off >>= 1) {
                    ull o = __shfl_xor(g, off);
                    if (o < g) g = o;
                }
                wm = g;
                wb = __ballot(lm == wm);
                wl = (int)__ffsll((long long)wb) - 1;
            } else {
                wl = (int)__ffsll((long long)wb) - 1;
                wm = ((ull)mh << 32) | (ull)__shfl(lo, wl);
            }
            if (lane == wl) {
                s_wkey[wave] = wm;
                s_wbox[wave][0] = x1[lj]; s_wbox[wave][1] = y1[lj];
                s_wbox[wave][2] = x2[lj]; s_wbox[wave][3] = y2[lj];
                s_wbox[wave][4] = ar[lj]; s_wbox[wave][5] = cf[lj];
            }
            __syncthreads();
            ull gk = s_wkey[0]; int gw = 0;
            #pragma unroll
            for (int w2 = 1; w2 < 4; w2++) {
                ull kk = s_wkey[w2];
                if (kk < gk) { gk = kk; gw = w2; }
            }
            if (gk == ~0ULL) break;               // uniform: all waves empty
            float cx1 = s_wbox[gw][0], cy1 = s_wbox[gw][1];
            float cx2 = s_wbox[gw][2], cy2 = s_wbox[gw][3];
            float a1 = s_wbox[gw][4];
            if (t == 0) { pkey[np] = gk; pconf[np] = s_wbox[gw][5]; }
            np++;
            #pragma unroll
            for (int j = 0; j < 4; j++) {         // winner self-kills via IoU=1
                float xx1 = fmaxf(cx1, x1[j]), yy1 = fmaxf(cy1, y1[j]);
                float xx2 = fminf(cx2, x2[j]), yy2 = fminf(cy2, y2[j]);
                float iw = xx2 - xx1 + 1.0f, ih = yy2 - yy1 + 1.0f;
                float inter = fmaxf(iw, 0.0f) * fmaxf(ih, 0.0f);
                float iou = inter / (a1 + ar[j] - inter + 1e-16f);
                if (iou > 0.4f) k4[j] = ~0ULL;    // NMS_THRES
            }
            __syncthreads();                      // protect mailbox reuse
        }

        const int npw = np;                       // np <= 300 by construction
        if (t == 0 && npw) s_base = atomicAdd(pool_count, npw);
        __syncthreads();
        for (int j = t; j < npw; j += 256) {
            int pp = s_base + j;
            if (pp < POOL) {
                ull gm = pkey[j];
                // repack: bit63=0 | 31 score bits | 18 orig_idx | 14 pool_idx
                ull pk = ((ull)((unsigned)(gm >> 32) & 0x7FFFFFFFu) << 32)
                       | ((gm & 0xFFFFFFFFull) << 14) | (ull)pp;
                __hip_atomic_store(&pool_key[pp], pk,
                                   __ATOMIC_RELAXED, __HIP_MEMORY_SCOPE_AGENT);
                __hip_atomic_store(&pool_conf[pp], pconf[j],
                                   __ATOMIC_RELAXED, __HIP_MEMORY_SCOPE_AGENT);
                __hip_atomic_store(&pool_cls[pp], c,
                                   __ATOMIC_RELAXED, __HIP_MEMORY_SCOPE_AGENT);
            }
        }
    }

    gsync(done_count, 2 * NBLK, t);   // all pool writes at coherent point
    if (bid != 0) return;

    // ================= final stage (block 0, all 256 threads) ===================
    const int K = min(__hip_atomic_load(pool_count, __ATOMIC_RELAXED,
                                        __HIP_MEMORY_SCOPE_AGENT), POOL);
    ull key[32];
    #pragma unroll
    for (int j = 0; j < 32; j++) {
        int pos = t + (j << 8);
        key[j] = (pos < K) ? __hip_atomic_load(&pool_key[pos], __ATOMIC_RELAXED,
                                               __HIP_MEMORY_SCOPE_AGENT)
                           : ~0ULL;
    }

    const bool selAll = (K <= 511);
    int sh = 55;            // digit = bits [sh+7 : sh]
    ull pfin = 0;           // sel iff (key >> sh) <= pfin
    if (!selAll) {
        // histogram radix select, 8 bits/pass; 1 pass typical.
        ull p = 0;
        int gBelow = 0, r = 300;
        while (true) {
            s_hist[t] = 0;
            __syncthreads();
            #pragma unroll
            for (int j = 0; j < 32; j++) {
                ull kk = key[j];
                if ((kk >> (sh + 8)) == p)
                    atomicAdd(&s_hist[(int)((kk >> sh) & 0xFFull)], 1);
            }
            __syncthreads();
            int v = s_hist[t];
            int incv = v;
            for (int off = 1; off < 64; off <<= 1) {
                int o = __shfl_up(incv, off);
                if (lane >= off) incv += o;
            }
            if (lane == 63) s_wt[wave] = incv;
            __syncthreads();
            int wo = 0;
            #pragma unroll
            for (int w2 = 0; w2 < 4; w2++) if (w2 < wave) wo += s_wt[w2];
            int cumIncl = wo + incv;
            int cumExcl = cumIncl - v;
            if (cumExcl < r && r <= cumIncl) {    // unique straddling bin
                s_stat[0] = t; s_stat[1] = cumExcl; s_stat[2] = cumIncl;
            }
            __syncthreads();
            int D = s_stat[0], below = s_stat[1], incl = s_stat[2];
            if (gBelow + incl <= 511 || sh == 7) {   // sh==7 provably fits
                pfin = (p << 8) | (ull)D;
                break;
            }
            p = (p << 8) | (ull)D;
            gBelow += below;
            r = 300 - gBelow;
            sh -= 8;
            __syncthreads();
        }
    }

    if (t == 0) s_stat[3] = 0;
    __syncthreads();
    int ci = 0;
    #pragma unroll
    for (int j = 0; j < 32; j++) {
        ull kk = key[j];
        bool sel = selAll ? ((kk >> 63) == 0) : ((kk >> sh) <= pfin);
        if (sel) ci++;
    }
    int inc = ci;
    for (int off = 1; off < 64; off <<= 1) {
        int o = __shfl_up(inc, off);
        if (lane >= off) inc += o;
    }
    int wtot = __shfl(inc, 63);
    int wbase2 = 0;
    if (lane == 0 && wtot) wbase2 = atomicAdd(&s_stat[3], wtot);
    wbase2 = __shfl(wbase2, 0);
    int wp = wbase2 + inc - ci;
    #pragma unroll
    for (int j = 0; j < 32; j++) {
        ull kk = key[j];
        bool sel = selAll ? ((kk >> 63) == 0) : ((kk >> sh) <= pfin);
        if (sel) s_buf[wp++] = kk;
    }
    __syncthreads();
    const int S = s_stat[3];
    for (int i = t; i < 512; i += 256) if (i >= S) s_buf[i] = ~0ULL;
    __syncthreads();
    if (wave != 0) return;

    #pragma clang loop unroll(disable)
    for (int pass = 0; pass < 2; pass++) {
        ull x[8];
        #pragma unroll
        for (int r2 = 0; r2 < 8; r2++) x[r2] = s_buf[(r2 << 6) + lane];
        bsort512(x, lane);
        if (pass == 0) {
            #pragma unroll
            for (int r2 = 0; r2 < 8; r2++) {
                int i = (r2 << 6) + lane;
                ull kk = x[r2];
                ull k2 = ~0ULL;
                if (i < 300 && kk != ~0ULL) {
                    int pidx = (int)(kk & 0x3FFFull);
                    unsigned cb = __float_as_uint(
                        __hip_atomic_load(&pool_conf[pidx], __ATOMIC_RELAXED,
                                          __HIP_MEMORY_SCOPE_AGENT));
                    unsigned cl = (unsigned)__hip_atomic_load(&pool_cls[pidx],
                                          __ATOMIC_RELAXED, __HIP_MEMORY_SCOPE_AGENT);
                    s_cb[i] = cb; s_cl[i] = cl;
                    k2 = ((ull)(~cb) << 32) | (unsigned)(~i);   // conf desc, rank desc
                }
                s_buf[i] = k2;
            }
        } else {
            #pragma unroll
            for (int r2 = 0; r2 < 8; r2++) {
                int i = (r2 << 6) + lane;
                if (i < 300) {
                    ull kk = x[r2];
                    float idv = 0.0f, pv = 0.0f;
                    if (kk != ~0ULL) {
                        int slot = (int)(~(unsigned)(kk & 0xFFFFFFFFull));
                        pv = __uint_as_float(s_cb[slot]);
                        idv = (float)(int)s_cl[slot];
                    }
                    out[i] = idv;        // ids (1,300)
                    out[300 + i] = pv;   // probs (300,)
                }
            }
        }
    }
}

extern "C" void kernel_launch(void* const* d_in, const int* in_sizes, int n_in,
                              void* d_out, int out_size, void* d_ws, size_t ws_size,
                              hipStream_t stream) {
    const float* det = (const float*)d_in[0];
    float* out = (float*)d_out;
    char* ws = (char*)d_ws;

    int* cnt_pad = (int*)(ws + 0);                // 80*8*16*4 = 40960 (1 counter / 64B line)
    int* pool_count = (int*)(ws + 40960);         // 4
    int* done_count = (int*)(ws + 40964);         // 4
    ull* key2 = (ull*)(ws + 41024);               // 80*1024*8 = 655360
    float* conf2 = (float*)(ws + 696384);         // 80*1024*4 = 327680
    float4* box2 = (float4*)(ws + 1024064);       // 80*1024*16 = 1310720 (16B aligned)
    ull* pool_key = (ull*)(ws + 2334784);         // POOL*8 = 65536
    float* pool_conf = (float*)(ws + 2400320);    // POOL*4 = 32768
    int* pool_cls = (int*)(ws + 2433088);         // POOL*4 = 32768

    k_init<<<1, 1024, 0, stream>>>(cnt_pad, pool_count, done_count);
    k_mega<<<NBLK, 256, 0, stream>>>(det, cnt_pad, key2, conf2, box2,
                                     pool_key, pool_conf, pool_cls, pool_count,
                                     done_count, out);
}

// Round 12
// 171.740 us; speedup vs baseline: 1.1241x; 1.1241x over previous
//
#include <hip/hip_runtime.h>

#pragma clang fp contract(off)

#define NBOX 262144
#define NCLS 80
#define ROWS 85
#define CAP 1024
#define NSUB 8          // sub-buckets per class (contention spreading)
#define SUBCAP 128      // CAP / NSUB; mean load ~82, 5 sigma headroom
#define POOL 8192
#define BPT 2           // boxes per thread in stage1 (MLP for strided obj loads)
#define S1BOX 512       // boxes per stage1 block

typedef unsigned long long ull;

// ---------------- init: zero padded per-(class,sub) counters + pool/done counters
__global__ __launch_bounds__(1024) void k_init(int* __restrict__ cnt_pad,
                                               int* __restrict__ pool_count,
                                               int* __restrict__ done_count) {
    const int t = threadIdx.x;
    for (int i = t; i < NCLS * NSUB * 16; i += 1024) cnt_pad[i] = 0;
    if (t == 0) { *pool_count = 0; *done_count = 0; }
}

// ---------------- stage1: obj-scan (BPT boxes/thread MLP) + class argmax + bucket scatter
__global__ __launch_bounds__(256) void k_stage1(const float* __restrict__ det,
                                                int* __restrict__ cnt_pad,
                                                ull* __restrict__ key2,
                                                float* __restrict__ conf2,
                                                float4* __restrict__ box2) {
    __shared__ int s_wl[S1BOX];
    __shared__ float s_obj[S1BOX];
    __shared__ int s_nv;
    const int t = threadIdx.x;
    const int b0 = blockIdx.x * S1BOX;
    const int sb = blockIdx.x & (NSUB - 1);   // this block's sub-bucket

    if (t == 0) s_nv = 0;
    __syncthreads();

    // phase 1: BPT independent strided obj loads per thread (latency hiding)
    float obj[BPT];
    #pragma unroll
    for (int i = 0; i < BPT; i++)
        obj[i] = det[(size_t)(b0 + (i << 8) + t) * ROWS + 4];
    #pragma unroll
    for (int i = 0; i < BPT; i++) {
        if (obj[i] >= 0.8f) {                 // CONF_THRES
            int r = atomicAdd(&s_nv, 1);      // LDS atomic; worklist order irrelevant
            s_wl[r] = (i << 8) + t;
            s_obj[r] = obj[i];
        }
    }
    __syncthreads();
    const int nv = s_nv;

    // phase 2: 16 lanes per valid box; j = k*16 + c covers classes 0..79 exactly
    const int grp = t >> 4, c = t & 15;
    const int lane = t & 63;
    #pragma unroll 4
    for (int r0 = 0; r0 < nv; r0 += 16) {
        int widx = r0 + grp;
        if (widx < nv) {                      // group-uniform guard (widx dep. on grp only)
            int b = s_wl[widx];
            const float* p = det + (size_t)(b0 + b) * ROWS;
            float aux = (c < 5) ? p[c] : 0.0f;    // x y w h obj
            float v0 = p[5 + c];
            float v1 = p[21 + c];
            float v2 = p[37 + c];
            float v3 = p[53 + c];
            float v4 = p[69 + c];
            float mv = v0; int mj = c;
            if (v1 > mv) { mv = v1; mj = 16 + c; }   // ascending j, strict >
            if (v2 > mv) { mv = v2; mj = 32 + c; }
            if (v3 > mv) { mv = v3; mj = 48 + c; }
            if (v4 > mv) { mv = v4; mj = 64 + c; }
            #pragma unroll
            for (int off = 8; off; off >>= 1) {      // group argmax, ties smaller j
                float ov = __shfl_xor(mv, off);
                int oj = __shfl_xor(mj, off);
                if (ov > mv || (ov == mv && oj < mj)) { mv = ov; mj = oj; }
            }
            int gb = lane & 48;                      // group base within wave
            float x = __shfl(aux, gb + 0);
            float y = __shfl(aux, gb + 1);
            float w = __shfl(aux, gb + 2);
            float h = __shfl(aux, gb + 3);
            if (c == 0) {
                float ob = s_obj[widx];
                float score = ob * mv;
                float hw = w * 0.5f, hh = h * 0.5f;
                int gi = b0 + b;
                int r = atomicAdd(&cnt_pad[((mj * NSUB + sb) << 4)], 1);
                if (r < SUBCAP) {
                    int pos = (mj << 10) + (sb << 7) + r;
                    key2[pos] = ((ull)(~__float_as_uint(score)) << 32) | (unsigned)gi;
                    conf2[pos] = mv;
                    box2[pos] = make_float4(x - hw, y - hh, x + hw, y + hh);
                }
            }
        }
    }
}

// ---------------- single-wave in-register bitonic sort of 512 (8/lane, i = r*64+lane)
__device__ __forceinline__ void bsort512(ull (&x)[8], int lane) {
    #pragma unroll
    for (int k = 2; k <= 512; k <<= 1) {
        #pragma unroll
        for (int j = k >> 1; j >= 64; j >>= 1) {
            const int jr = j >> 6;
            #pragma unroll
            for (int r2 = 0; r2 < 8; r2++) {
                if ((r2 & jr) == 0) {
                    const bool asc = (((r2 << 6) & k) == 0);
                    ull a = x[r2], b = x[r2 | jr];
                    if ((a > b) == asc) { x[r2] = b; x[r2 | jr] = a; }
                }
            }
        }
        #pragma unroll
        for (int j = ((k >> 1) > 32 ? 32 : (k >> 1)); j >= 1; j >>= 1) {
            #pragma unroll
            for (int r2 = 0; r2 < 8; r2++) {
                int i = (r2 << 6) + lane;
                bool asc = ((i & k) == 0);
                ull o = __shfl_xor(x[r2], j);
                bool lower = ((lane & j) == 0);
                ull mn = x[r2] < o ? x[r2] : o;
                ull mx2 = x[r2] < o ? o : x[r2];
                x[r2] = (asc == lower) ? mn : mx2;
            }
        }
    }
}

// ---------------- stage2+3+4: 4-wave cooperative per-class NMS (boxes in REGISTERS,
// 4 slots/thread/wave) + last-ticket fused final. Per pick: wave-local argmin ->
// 4-entry LDS mailbox -> barrier -> uniform global min -> all waves kill own slots
// in pure VALU -> barrier. Cross-XCD pool visibility via agent-scope relaxed atomic
// stores + vmcnt drain + device-scope ticket (validated R6-R9).
__global__ __launch_bounds__(256) void k_nmsfinal(const int* __restrict__ cnt_pad,
                                                  const ull* __restrict__ key2,
                                                  const float* __restrict__ conf2,
                                                  const float4* __restrict__ box2,
                                                  ull* __restrict__ pool_key,
                                                  float* __restrict__ pool_conf,
                                                  int* __restrict__ pool_cls,
                                                  int* __restrict__ pool_count,
                                                  int* __restrict__ done_count,
                                                  float* __restrict__ out) {
    __shared__ int s_cnt[NSUB];
    __shared__ ull s_wkey[4];        // per-wave winner mailbox
    __shared__ float s_wbox[4][6];   // x1 y1 x2 y2 area conf
    __shared__ int s_base;
    __shared__ int s_fin;
    __shared__ ull pkey[304];
    __shared__ float pconf[304];
    // final-stage shared
    __shared__ int s_hist[256];
    __shared__ int s_wt[4];
    __shared__ int s_stat[4];   // [0]=D [1]=cumExcl [2]=cumIncl [3]=compaction base
    __shared__ ull s_buf[512];
    __shared__ unsigned s_cb[512];
    __shared__ unsigned s_cl[512];

    const int c = blockIdx.x, t = threadIdx.x, lane = t & 63, wave = t >> 6;
    const int s0 = c << 10;

    // ---- staging: each wave owns 256 boxes (4 slots/lane), global -> registers ----
    ull k4[4]; float x1[4], y1[4], x2[4], y2[4], ar[4], cf[4];
    #pragma unroll
    for (int j = 0; j < 4; j++) {
        int pos = (wave << 8) + (j << 6) + lane;      // coalesced 64-lane segments
        k4[j] = key2[s0 + pos];
        float4 b = box2[s0 + pos];
        x1[j] = b.x; y1[j] = b.y; x2[j] = b.z; y2[j] = b.w;
        cf[j] = conf2[s0 + pos];
    }
    if (t < NSUB) s_cnt[t] = min(cnt_pad[((c * NSUB + t) << 4)], SUBCAP);
    __syncthreads();
    #pragma unroll
    for (int j = 0; j < 4; j++) {
        int pos = (wave << 8) + (j << 6) + lane;
        bool ok = (pos & (SUBCAP - 1)) < s_cnt[pos >> 7];   // gaps masked; poison never used
        if (!ok) {
            k4[j] = ~0ULL;
            x1[j] = 0.f; y1[j] = 0.f; x2[j] = 0.f; y2[j] = 0.f; cf[j] = 0.f;
        }
        ar[j] = (x2[j] - x1[j] + 1.0f) * (y2[j] - y1[j] + 1.0f);
    }

    int np = 0;
    while (np < 300) {
        // wave-local argmin over 4 slots (depth-2 tree)
        ull va = k4[0]; int ia = 0;
        if (k4[1] < va) { va = k4[1]; ia = 1; }
        ull vb = k4[2]; int ib = 2;
        if (k4[3] < vb) { vb = k4[3]; ib = 3; }
        ull lm = va; int lj = ia;
        if (vb < va) { lm = vb; lj = ib; }
        unsigned lo = (unsigned)lm;
        unsigned hi = (unsigned)(lm >> 32);
        // 32-bit wave min over hi word (scores); exact fallback (NON-breaking:
        // empty waves still post ~0 and reach both barriers)
        unsigned mh = hi;
        #pragma unroll
        for (int off = 32; off; off >>= 1) {
            unsigned o = __shfl_xor(mh, off);
            mh = o < mh ? o : mh;
        }
        ull wb = __ballot(hi == mh);
        ull wm; int wl;
        if (__popcll(wb) != 1) {
            ull g = (hi == mh) ? lm : ~0ULL;
            #pragma unroll
            for (int off = 32; off; off >>= 1) {
                ull o = __shfl_xor(g, off);
                if (o < g) g = o;
            }
            wm = g;                                   // ~0 iff wave empty
            wb = __ballot(lm == wm);
            wl = (int)__ffsll((long long)wb) - 1;
        } else {
            wl = (int)__ffsll((long long)wb) - 1;
            wm = ((ull)mh << 32) | (ull)__shfl(lo, wl);
        }
        if (lane == wl) {                             // winner lane posts key + payload
            s_wkey[wave] = wm;
            s_wbox[wave][0] = x1[lj]; s_wbox[wave][1] = y1[lj];
            s_wbox[wave][2] = x2[lj]; s_wbox[wave][3] = y2[lj];
            s_wbox[wave][4] = ar[lj]; s_wbox[wave][5] = cf[lj];
        }
        __syncthreads();
        ull gk = s_wkey[0]; int gw = 0;               // uniform global min of 4
        #pragma unroll
        for (int w2 = 1; w2 < 4; w2++) {
            ull kk = s_wkey[w2];
            if (kk < gk) { gk = kk; gw = w2; }
        }
        if (gk == ~0ULL) break;                       // uniform: all waves empty
        float cx1 = s_wbox[gw][0], cy1 = s_wbox[gw][1];
        float cx2 = s_wbox[gw][2], cy2 = s_wbox[gw][3];
        float a1 = s_wbox[gw][4];
        if (t == 0) { pkey[np] = gk; pconf[np] = s_wbox[gw][5]; }
        np++;
        // kill own 4 slots, pure VALU, no guard (re-killing dead is a no-op;
        // winner self-kills via IoU=1)
        #pragma unroll
        for (int j = 0; j < 4; j++) {
            float xx1 = fmaxf(cx1, x1[j]), yy1 = fmaxf(cy1, y1[j]);
            float xx2 = fminf(cx2, x2[j]), yy2 = fminf(cy2, y2[j]);
            float iw = xx2 - xx1 + 1.0f, ih = yy2 - yy1 + 1.0f;
            float inter = fmaxf(iw, 0.0f) * fmaxf(ih, 0.0f);
            float iou = inter / (a1 + ar[j] - inter + 1e-16f);
            if (iou > 0.4f) k4[j] = ~0ULL;            // NMS_THRES
        }
        __syncthreads();                              // protect mailbox reuse
    }

    const int npw = np;                               // np <= 300 by construction
    if (t == 0 && npw) s_base = atomicAdd(pool_count, npw);
    __syncthreads();
    for (int j = t; j < npw; j += 256) {
        int pp = s_base + j;
        if (pp < POOL) {
            ull gm = pkey[j];
            // repack: bit63=0 | 31 score bits | 18 orig_idx | 14 pool_idx
            ull pk = ((ull)((unsigned)(gm >> 32) & 0x7FFFFFFFu) << 32)
                   | ((gm & 0xFFFFFFFFull) << 14) | (ull)pp;
            __hip_atomic_store(&pool_key[pp], pk,
                               __ATOMIC_RELAXED, __HIP_MEMORY_SCOPE_AGENT);
            __hip_atomic_store(&pool_conf[pp], pconf[j],
                               __ATOMIC_RELAXED, __HIP_MEMORY_SCOPE_AGENT);
            __hip_atomic_store(&pool_cls[pp], c,
                               __ATOMIC_RELAXED, __HIP_MEMORY_SCOPE_AGENT);
        }
    }
    // completion (not flush): coherent-point stores just need vmcnt retire
    asm volatile("s_waitcnt vmcnt(0)" ::: "memory");
    __syncthreads();
    if (t == 0) {
        int ticket = atomicAdd(done_count, 1);        // device-scope total order
        s_fin = (ticket == NCLS - 1) ? 1 : 0;
    }
    __syncthreads();
    if (!s_fin) return;

    // ---- fused final stage (all 256 threads of the last-done block) ----
    const int K = min(__hip_atomic_load(pool_count, __ATOMIC_RELAXED,
                                        __HIP_MEMORY_SCOPE_AGENT), POOL);
    ull key[32];
    #pragma unroll
    for (int j = 0; j < 32; j++) {
        int pos = t + (j << 8);
        key[j] = (pos < K) ? __hip_atomic_load(&pool_key[pos], __ATOMIC_RELAXED,
                                               __HIP_MEMORY_SCOPE_AGENT)
                           : ~0ULL;
    }

    const bool selAll = (K <= 511);
    int sh = 55;            // digit = bits [sh+7 : sh]
    ull pfin = 0;           // final threshold prefix: sel iff (key >> sh) <= pfin
    if (!selAll) {
        // histogram radix select, 8 bits/pass; 1 pass typical (bin occupancy ~K/256).
        ull p = 0;
        int gBelow = 0, r = 300;
        while (true) {
            s_hist[t] = 0;
            __syncthreads();
            #pragma unroll
            for (int j = 0; j < 32; j++) {
                ull kk = key[j];
                if ((kk >> (sh + 8)) == p)
                    atomicAdd(&s_hist[(int)((kk >> sh) & 0xFFull)], 1);
            }
            __syncthreads();
            // 256-bin inclusive scan: per-wave shfl scan + wave offsets
            int v = s_hist[t];
            int incv = v;
            for (int off = 1; off < 64; off <<= 1) {
                int o = __shfl_up(incv, off);
                if (lane >= off) incv += o;
            }
            if (lane == 63) s_wt[wave] = incv;
            __syncthreads();
            int wo = 0;
            #pragma unroll
            for (int w2 = 0; w2 < 4; w2++) if (w2 < wave) wo += s_wt[w2];
            int cumIncl = wo + incv;
            int cumExcl = cumIncl - v;
            // unique straddling bin: cumExcl < r <= cumIncl
            if (cumExcl < r && r <= cumIncl) {
                s_stat[0] = t; s_stat[1] = cumExcl; s_stat[2] = cumIncl;
            }
            __syncthreads();
            int D = s_stat[0], below = s_stat[1], incl = s_stat[2];
            if (gBelow + incl <= 511 || sh == 7) {   // sh==7 provably fits (<=299+128)
                pfin = (p << 8) | (ull)D;
                break;
            }
            p = (p << 8) | (ull)D;
            gBelow += below;
            r = 300 - gBelow;
            sh -= 8;
            __syncthreads();   // protect s_hist/s_stat reuse next pass
        }
    }

    if (t == 0) s_stat[3] = 0;
    __syncthreads();
    int ci = 0;
    #pragma unroll
    for (int j = 0; j < 32; j++) {
        ull kk = key[j];
        bool sel = selAll ? ((kk >> 63) == 0) : ((kk >> sh) <= pfin);
        if (sel) ci++;
    }
    int inc = ci;
    for (int off = 1; off < 64; off <<= 1) {
        int o = __shfl_up(inc, off);
        if (lane >= off) inc += o;
    }
    int wtot = __shfl(inc, 63);
    int wbase2 = 0;
    if (lane == 0 && wtot) wbase2 = atomicAdd(&s_stat[3], wtot);
    wbase2 = __shfl(wbase2, 0);
    int wp = wbase2 + inc - ci;
    #pragma unroll
    for (int j = 0; j < 32; j++) {
        ull kk = key[j];
        bool sel = selAll ? ((kk >> 63) == 0) : ((kk >> sh) <= pfin);
        if (sel) s_buf[wp++] = kk;
    }
    __syncthreads();
    const int S = s_stat[3];
    for (int i = t; i < 512; i += 256) if (i >= S) s_buf[i] = ~0ULL;
    __syncthreads();
    if (wave != 0) return;

    #pragma clang loop unroll(disable)
    for (int pass = 0; pass < 2; pass++) {
        ull x[8];
        #pragma unroll
        for (int r2 = 0; r2 < 8; r2++) x[r2] = s_buf[(r2 << 6) + lane];
        bsort512(x, lane);
        if (pass == 0) {
            #pragma unroll
            for (int r2 = 0; r2 < 8; r2++) {
                int i = (r2 << 6) + lane;
                ull kk = x[r2];
                ull k2 = ~0ULL;
                if (i < 300 && kk != ~0ULL) {
                    int pidx = (int)(kk & 0x3FFFull);
                    unsigned cb = __float_as_uint(
                        __hip_atomic_load(&pool_conf[pidx], __ATOMIC_RELAXED,
                                          __HIP_MEMORY_SCOPE_AGENT));
                    unsigned cl = (unsigned)__hip_atomic_load(&pool_cls[pidx],
                                          __ATOMIC_RELAXED, __HIP_MEMORY_SCOPE_AGENT);
                    s_cb[i] = cb; s_cl[i] = cl;
                    k2 = ((ull)(~cb) << 32) | (unsigned)(~i);   // conf desc, rank desc
                }
                s_buf[i] = k2;
            }
        } else {
            #pragma unroll
            for (int r2 = 0; r2 < 8; r2++) {
                int i = (r2 << 6) + lane;
                if (i < 300) {
                    ull kk = x[r2];
                    float idv = 0.0f, pv = 0.0f;
                    if (kk != ~0ULL) {
                        int slot = (int)(~(unsigned)(kk & 0xFFFFFFFFull));
                        pv = __uint_as_float(s_cb[slot]);
                        idv = (float)(int)s_cl[slot];
                    }
                    out[i] = idv;        // ids (1,300)
                    out[300 + i] = pv;   // probs (300,)
                }
            }
        }
    }
}

extern "C" void kernel_launch(void* const* d_in, const int* in_sizes, int n_in,
                              void* d_out, int out_size, void* d_ws, size_t ws_size,
                              hipStream_t stream) {
    const float* det = (const float*)d_in[0];
    float* out = (float*)d_out;
    char* ws = (char*)d_ws;

    int* cnt_pad = (int*)(ws + 0);                // 80*8*16*4 = 40960 (1 counter / 64B line)
    int* pool_count = (int*)(ws + 40960);         // 4
    int* done_count = (int*)(ws + 40964);         // 4
    ull* key2 = (ull*)(ws + 41024);               // 80*1024*8 = 655360
    float* conf2 = (float*)(ws + 696384);         // 80*1024*4 = 327680
    float4* box2 = (float4*)(ws + 1024064);       // 80*1024*16 = 1310720 (16B aligned)
    ull* pool_key = (ull*)(ws + 2334784);         // POOL*8 = 65536
    float* pool_conf = (float*)(ws + 2400320);    // POOL*4 = 32768
    int* pool_cls = (int*)(ws + 2433088);         // POOL*4 = 32768

    k_init<<<1, 1024, 0, stream>>>(cnt_pad, pool_count, done_count);
    k_stage1<<<NBOX / S1BOX, 256, 0, stream>>>(det, cnt_pad, key2, conf2, box2);
    k_nmsfinal<<<NCLS, 256, 0, stream>>>(cnt_pad, key2, conf2, box2,
                                         pool_key, pool_conf, pool_cls, pool_count,
                                         done_count, out);
}